// Round 2
// baseline (1434.228 us; speedup 1.0000x reference)
//
#include <hip/hip_runtime.h>

typedef unsigned short u16;
typedef _Float16 f16;
typedef f16 f16x8 __attribute__((ext_vector_type(8)));
typedef float f32x4 __attribute__((ext_vector_type(4)));

constexpr int N_NODES = 50000;
constexpr int E_EDGES = 800000;

// workspace layout (bytes)
constexpr size_t OFF_SCAT = 200704;                       // N*2*4
constexpr size_t OFF_MI   = 601088;                       // N*128*4
constexpr size_t MI_BYTES = (size_t)N_NODES * 128 * 4;    // 25,600,000
constexpr size_t OFF_H    = OFF_MI + MI_BYTES;            // h f32
constexpr size_t OFF_W    = OFF_H + MI_BYTES;             // f16 swizzled weights (512 KB)

// f32 -> f16 hi/lo split: x ~= hi + lo, |err| <= 2^-22 |x|
__device__ __forceinline__ void split_f(float x, f16& h, f16& l) {
    h = (f16)x;
    l = (f16)(x - (float)h);
}

__device__ __forceinline__ f32x4 mfma3(f16x8 ah, f16x8 al, f16x8 bh, f16x8 bl, f32x4 acc) {
    acc = __builtin_amdgcn_mfma_f32_16x16x32_f16(ah, bh, acc, 0, 0, 0);
    acc = __builtin_amdgcn_mfma_f32_16x16x32_f16(al, bh, acc, 0, 0, 0);
    acc = __builtin_amdgcn_mfma_f32_16x16x32_f16(ah, bl, acc, 0, 0, 0);
    return acc;
}

// ---- prep: swizzle weights into fragment-order hi/lo f16 planes ----
// layout: flat = (((ct*K32 + kk)*2 + plane)*64 + lane)*8 + j
// where col = ct*16 + (lane&15), k = kk*32 + (lane>>4)*8 + j
__global__ __launch_bounds__(256) void prep_kernel(
    const float* __restrict__ eW1, const float* __restrict__ eW2,
    const float* __restrict__ nW1, const float* __restrict__ nW2,
    const float* __restrict__ vW1, const float* __restrict__ cW1,
    f16* __restrict__ eW1s, f16* __restrict__ eW2s,
    f16* __restrict__ nW1s, f16* __restrict__ nW2s,
    f16* __restrict__ vW1s, f16* __restrict__ cW1s)
{
    const int gid = blockIdx.x * 256 + threadIdx.x;   // 131072 total
    const float* W; f16* out; int K32; int e;
    if (gid < 32768)       { W = eW1; out = eW1s; K32 = 8; e = gid; }
    else if (gid < 49152)  { W = eW2; out = eW2s; K32 = 4; e = gid - 32768; }
    else if (gid < 81920)  { W = nW1; out = nW1s; K32 = 8; e = gid - 49152; }
    else if (gid < 98304)  { W = nW2; out = nW2s; K32 = 4; e = gid - 81920; }
    else if (gid < 114688) { W = vW1; out = vW1s; K32 = 4; e = gid - 98304; }
    else                   { W = cW1; out = cW1s; K32 = 4; e = gid - 114688; }
    const int per = 512 * K32;
    const int ct = e / per, rem = e % per;
    const int kk = rem >> 9, lane = (rem >> 3) & 63, j = rem & 7;
    const int col = ct * 16 + (lane & 15);
    const int k = kk * 32 + ((lane >> 4) & 3) * 8 + j;
    const float v = W[k * 128 + col];
    f16 h, l; split_f(v, h, l);
    const int base = ((ct * K32 + kk) * 2) * 512 + lane * 8 + j;
    out[base] = h;
    out[base + 512] = l;
}

// ---- degree count ----
__global__ __launch_bounds__(256) void cnt_kernel(const int* __restrict__ eidx,
                                                  float* __restrict__ cnt) {
    const int e = blockIdx.x * 256 + threadIdx.x;
    if (e < E_EDGES) atomicAdd(&cnt[eidx[e]], 1.0f);
}

// ---- embedding (f32 VALU, tiny) ----
__global__ __launch_bounds__(256) void embed_kernel(
    const float* __restrict__ h_in, const float* __restrict__ embW,
    const float* __restrict__ embb, float* __restrict__ h)
{
    const int gid = blockIdx.x * 256 + threadIdx.x;
    if (gid >= N_NODES * 128) return;
    const int n = gid >> 7, j = gid & 127;
    float s = embb[j];
#pragma unroll
    for (int p = 0; p < 16; ++p) s += h_in[n * 16 + p] * embW[p * 128 + j];
    h[gid] = s;
}

// ---- edge kernel: m_ij MLP (hi/lo f16) + atomic segment-sum (+ coord & scatter) ----
__global__ __launch_bounds__(256) void edge_kernel(
    const int* __restrict__ eidx, const float* __restrict__ x,
    const float* __restrict__ h,
    const f16* __restrict__ eW1s, const float* __restrict__ eW1,
    const float* __restrict__ eb1,
    const f16* __restrict__ eW2s, const float* __restrict__ eb2,
    const f16* __restrict__ cW1s, const float* __restrict__ cb1,
    const float* __restrict__ cW2, const float* __restrict__ cb2,
    float* __restrict__ m_i, float* __restrict__ scat, const int do_coord)
{
    constexpr int SA = 520, SZ = 264;   // strides: 1040B/528B -> 4 mod 32 banks (2-way = free)
    __shared__ f16 smA[64 * SA];        // K=256 hi/lo octet-interleaved: [8hi|8lo] per octet
    __shared__ f16 smZ[64 * SZ];        // K=128 hidden
    __shared__ int smRow[64];
    __shared__ float smRd[64], smP2x[64], smP2y[64];
    __shared__ float smPart[4][64];
    f16* smM = smA;                     // m_ij tile (K=128) reuses smA after GEMM1

    const int t = threadIdx.x;
    const int base = blockIdx.x * 64;

    if (t < 64) {
        const int e = base + t;
        const int r = eidx[e], c = eidx[E_EDGES + e];
        smRow[t] = r;
        const float dx = x[2 * r] - x[2 * c];
        const float dy = x[2 * r + 1] - x[2 * c + 1];
        smRd[t] = dx * dx + dy * dy;
        smP2x[t] = dx * dx - dy * dy;     // rel_dist*cos(2θ) exactly
        smP2y[t] = 2.0f * dx * dy;        // rel_dist*sin(2θ) exactly
    }
    // stage A = [h[row] | h[col]] as hi/lo f16
#pragma unroll
    for (int it = 0; it < 8; ++it) {
        const int idx = it * 256 + t;               // 64 edges x 32 octets
        const int el = idx >> 5, seg = idx & 31;
        const int e = base + el;
        const int node = (seg < 16) ? eidx[e] : eidx[E_EDGES + e];
        const int k0 = (seg & 15) * 8;
        const float4 f0 = *(const float4*)(h + (size_t)node * 128 + k0);
        const float4 f1 = *(const float4*)(h + (size_t)node * 128 + k0 + 4);
        const float xs[8] = {f0.x, f0.y, f0.z, f0.w, f1.x, f1.y, f1.z, f1.w};
        f16x8 vh, vl;
#pragma unroll
        for (int i = 0; i < 8; ++i) { f16 hh, ll; split_f(xs[i], hh, ll); vh[i] = hh; vl[i] = ll; }
        f16* dst = &smA[el * SA + seg * 16];
        *(f16x8*)dst = vh;
        *(f16x8*)(dst + 8) = vl;
    }
    __syncthreads();

    const int lane = t & 63, w = t >> 6, qq = lane >> 4, nn = lane & 15;

    // ---- GEMM1: z = relu(feat @ eW1 + eb1), K=256 (+rel_dist row in epilogue) ----
    f32x4 acc1[4][2] = {};
    for (int kk = 0; kk < 8; ++kk) {
        f16x8 Ah[4], Al[4];
#pragma unroll
        for (int rt = 0; rt < 4; ++rt) {
            const f16* ap = &smA[(rt * 16 + nn) * SA + (kk * 4 + qq) * 16];
            Ah[rt] = *(const f16x8*)ap;
            Al[rt] = *(const f16x8*)(ap + 8);
        }
#pragma unroll
        for (int c = 0; c < 2; ++c) {
            const int ct = w * 2 + c;
            const f16* bp = eW1s + (size_t)((ct * 8 + kk) * 2) * 512 + lane * 8;
            const f16x8 Bh = *(const f16x8*)bp;
            const f16x8 Bl = *(const f16x8*)(bp + 512);
#pragma unroll
            for (int rt = 0; rt < 4; ++rt)
                acc1[rt][c] = mfma3(Ah[rt], Al[rt], Bh, Bl, acc1[rt][c]);
        }
    }
#pragma unroll
    for (int c = 0; c < 2; ++c) {
        const int col = w * 32 + c * 16 + nn;
        const float b1 = eb1[col];
        const float wl = eW1[256 * 128 + col];
#pragma unroll
        for (int rt = 0; rt < 4; ++rt) {
#pragma unroll
            for (int r = 0; r < 4; ++r) {
                const int el = rt * 16 + qq * 4 + r;
                const float z = fmaxf(acc1[rt][c][r] + b1 + smRd[el] * wl, 0.f);
                f16 zh, zl; split_f(z, zh, zl);
                f16* zp = &smZ[el * SZ + (col >> 3) * 16 + (col & 7)];
                zp[0] = zh; zp[8] = zl;
            }
        }
    }
    __syncthreads();

    // ---- GEMM2: m = z @ eW2 + eb2, K=128; atomic scatter into m_i ----
    f32x4 acc2[4][2] = {};
    for (int kk = 0; kk < 4; ++kk) {
        f16x8 Ah[4], Al[4];
#pragma unroll
        for (int rt = 0; rt < 4; ++rt) {
            const f16* ap = &smZ[(rt * 16 + nn) * SZ + (kk * 4 + qq) * 16];
            Ah[rt] = *(const f16x8*)ap;
            Al[rt] = *(const f16x8*)(ap + 8);
        }
#pragma unroll
        for (int c = 0; c < 2; ++c) {
            const int ct = w * 2 + c;
            const f16* bp = eW2s + (size_t)((ct * 4 + kk) * 2) * 512 + lane * 8;
            const f16x8 Bh = *(const f16x8*)bp;
            const f16x8 Bl = *(const f16x8*)(bp + 512);
#pragma unroll
            for (int rt = 0; rt < 4; ++rt)
                acc2[rt][c] = mfma3(Ah[rt], Al[rt], Bh, Bl, acc2[rt][c]);
        }
    }
#pragma unroll
    for (int c = 0; c < 2; ++c) {
        const int col = w * 32 + c * 16 + nn;
        const float b2 = eb2[col];
#pragma unroll
        for (int rt = 0; rt < 4; ++rt) {
#pragma unroll
            for (int r = 0; r < 4; ++r) {
                const int el = rt * 16 + qq * 4 + r;
                const float mv = acc2[rt][c][r] + b2;
                atomicAdd(&m_i[(size_t)smRow[el] * 128 + col], mv);
                if (do_coord) {
                    f16 mh, ml; split_f(mv, mh, ml);
                    f16* mp = &smM[el * SZ + (col >> 3) * 16 + (col & 7)];
                    mp[0] = mh; mp[8] = ml;
                }
            }
        }
    }

    if (do_coord) {
        __syncthreads();
        // ---- GEMM3: co = relu(m @ cW1 + cb1) @ cW2 + cb2 ; scatter rel_pos2*co ----
        f32x4 acc3[4][2] = {};
        for (int kk = 0; kk < 4; ++kk) {
            f16x8 Ah[4], Al[4];
#pragma unroll
            for (int rt = 0; rt < 4; ++rt) {
                const f16* ap = &smM[(rt * 16 + nn) * SZ + (kk * 4 + qq) * 16];
                Ah[rt] = *(const f16x8*)ap;
                Al[rt] = *(const f16x8*)(ap + 8);
            }
#pragma unroll
            for (int c = 0; c < 2; ++c) {
                const int ct = w * 2 + c;
                const f16* bp = cW1s + (size_t)((ct * 4 + kk) * 2) * 512 + lane * 8;
                const f16x8 Bh = *(const f16x8*)bp;
                const f16x8 Bl = *(const f16x8*)(bp + 512);
#pragma unroll
                for (int rt = 0; rt < 4; ++rt)
                    acc3[rt][c] = mfma3(Ah[rt], Al[rt], Bh, Bl, acc3[rt][c]);
            }
        }
        float p3[4][4];
#pragma unroll
        for (int rt = 0; rt < 4; ++rt)
#pragma unroll
            for (int r = 0; r < 4; ++r) p3[rt][r] = 0.f;
#pragma unroll
        for (int c = 0; c < 2; ++c) {
            const int col = w * 32 + c * 16 + nn;
            const float c1 = cb1[col];
            const float w2 = cW2[col];
#pragma unroll
            for (int rt = 0; rt < 4; ++rt)
#pragma unroll
                for (int r = 0; r < 4; ++r)
                    p3[rt][r] += fmaxf(acc3[rt][c][r] + c1, 0.f) * w2;
        }
#pragma unroll
        for (int off = 1; off < 16; off <<= 1)
#pragma unroll
            for (int rt = 0; rt < 4; ++rt)
#pragma unroll
                for (int r = 0; r < 4; ++r) p3[rt][r] += __shfl_xor(p3[rt][r], off);
        if (nn == 0) {
#pragma unroll
            for (int rt = 0; rt < 4; ++rt)
#pragma unroll
                for (int r = 0; r < 4; ++r)
                    smPart[w][rt * 16 + qq * 4 + r] = p3[rt][r];
        }
        __syncthreads();
        if (t < 64) {
            const float co = smPart[0][t] + smPart[1][t] + smPart[2][t] + smPart[3][t] + cb2[0];
            const int rw = smRow[t];
            atomicAdd(&scat[2 * rw],     smP2x[t] * co);
            atomicAdd(&scat[2 * rw + 1], smP2y[t] * co);
        }
    }
}

// ---- node kernel: h += MLP([h, m_i]) ----
__global__ __launch_bounds__(256) void node_kernel(
    float* __restrict__ h, const float* __restrict__ m_i,
    const f16* __restrict__ nW1s, const float* __restrict__ nb1,
    const f16* __restrict__ nW2s, const float* __restrict__ nb2)
{
    constexpr int SA = 520, SZ = 264;
    __shared__ f16 smA[64 * SA];
    __shared__ f16 smZ[64 * SZ];
    const int t = threadIdx.x;
    const int base = blockIdx.x * 64;

#pragma unroll
    for (int it = 0; it < 8; ++it) {
        const int idx = it * 256 + t;
        const int el = idx >> 5, seg = idx & 31;
        const int node = base + el;
        const int k0 = (seg & 15) * 8;
        float xs[8] = {0.f, 0.f, 0.f, 0.f, 0.f, 0.f, 0.f, 0.f};
        if (node < N_NODES) {
            const float* src = (seg < 16) ? (h + (size_t)node * 128 + k0)
                                          : (m_i + (size_t)node * 128 + k0);
            const float4 f0 = *(const float4*)src;
            const float4 f1 = *(const float4*)(src + 4);
            xs[0] = f0.x; xs[1] = f0.y; xs[2] = f0.z; xs[3] = f0.w;
            xs[4] = f1.x; xs[5] = f1.y; xs[6] = f1.z; xs[7] = f1.w;
        }
        f16x8 vh, vl;
#pragma unroll
        for (int i = 0; i < 8; ++i) { f16 hh, ll; split_f(xs[i], hh, ll); vh[i] = hh; vl[i] = ll; }
        f16* dst = &smA[el * SA + seg * 16];
        *(f16x8*)dst = vh;
        *(f16x8*)(dst + 8) = vl;
    }
    __syncthreads();

    const int lane = t & 63, w = t >> 6, qq = lane >> 4, nn = lane & 15;

    f32x4 acc1[4][2] = {};
    for (int kk = 0; kk < 8; ++kk) {
        f16x8 Ah[4], Al[4];
#pragma unroll
        for (int rt = 0; rt < 4; ++rt) {
            const f16* ap = &smA[(rt * 16 + nn) * SA + (kk * 4 + qq) * 16];
            Ah[rt] = *(const f16x8*)ap;
            Al[rt] = *(const f16x8*)(ap + 8);
        }
#pragma unroll
        for (int c = 0; c < 2; ++c) {
            const int ct = w * 2 + c;
            const f16* bp = nW1s + (size_t)((ct * 8 + kk) * 2) * 512 + lane * 8;
            const f16x8 Bh = *(const f16x8*)bp;
            const f16x8 Bl = *(const f16x8*)(bp + 512);
#pragma unroll
            for (int rt = 0; rt < 4; ++rt)
                acc1[rt][c] = mfma3(Ah[rt], Al[rt], Bh, Bl, acc1[rt][c]);
        }
    }
#pragma unroll
    for (int c = 0; c < 2; ++c) {
        const int col = w * 32 + c * 16 + nn;
        const float b1 = nb1[col];
#pragma unroll
        for (int rt = 0; rt < 4; ++rt) {
#pragma unroll
            for (int r = 0; r < 4; ++r) {
                const int el = rt * 16 + qq * 4 + r;
                const float z = fmaxf(acc1[rt][c][r] + b1, 0.f);
                f16 zh, zl; split_f(z, zh, zl);
                f16* zp = &smZ[el * SZ + (col >> 3) * 16 + (col & 7)];
                zp[0] = zh; zp[8] = zl;
            }
        }
    }
    __syncthreads();

    f32x4 acc2[4][2] = {};
    for (int kk = 0; kk < 4; ++kk) {
        f16x8 Ah[4], Al[4];
#pragma unroll
        for (int rt = 0; rt < 4; ++rt) {
            const f16* ap = &smZ[(rt * 16 + nn) * SZ + (kk * 4 + qq) * 16];
            Ah[rt] = *(const f16x8*)ap;
            Al[rt] = *(const f16x8*)(ap + 8);
        }
#pragma unroll
        for (int c = 0; c < 2; ++c) {
            const int ct = w * 2 + c;
            const f16* bp = nW2s + (size_t)((ct * 4 + kk) * 2) * 512 + lane * 8;
            const f16x8 Bh = *(const f16x8*)bp;
            const f16x8 Bl = *(const f16x8*)(bp + 512);
#pragma unroll
            for (int rt = 0; rt < 4; ++rt)
                acc2[rt][c] = mfma3(Ah[rt], Al[rt], Bh, Bl, acc2[rt][c]);
        }
    }
#pragma unroll
    for (int c = 0; c < 2; ++c) {
        const int col = w * 32 + c * 16 + nn;
        const float b2 = nb2[col];
#pragma unroll
        for (int rt = 0; rt < 4; ++rt) {
#pragma unroll
            for (int r = 0; r < 4; ++r) {
                const int el = rt * 16 + qq * 4 + r;
                const int node = base + el;
                if (node < N_NODES) {
                    const size_t ix = (size_t)node * 128 + col;
                    h[ix] = h[ix] + acc2[rt][c][r] + b2;
                }
            }
        }
    }
}

// ---- final: v = MLP_v(h) + scat/denom, L2-normalize; write h | x | v ----
__global__ __launch_bounds__(256) void final_kernel(
    const float* __restrict__ h, const float* __restrict__ x,
    const f16* __restrict__ vW1s, const float* __restrict__ vb1,
    const float* __restrict__ vW2, const float* __restrict__ vb2,
    const float* __restrict__ scat, const float* __restrict__ cnt,
    float* __restrict__ out)
{
    constexpr int SZ = 264;
    __shared__ f16 smA[64 * SZ];
    __shared__ f16 smZ[64 * SZ];
    const int t = threadIdx.x;
    const int base = blockIdx.x * 64;

#pragma unroll
    for (int it = 0; it < 4; ++it) {
        const int idx = it * 256 + t;               // 64 x 16 octets
        const int el = idx >> 4, seg = idx & 15;
        const int node = base + el;
        const int k0 = seg * 8;
        float xs[8] = {0.f, 0.f, 0.f, 0.f, 0.f, 0.f, 0.f, 0.f};
        if (node < N_NODES) {
            const float4 f0 = *(const float4*)(h + (size_t)node * 128 + k0);
            const float4 f1 = *(const float4*)(h + (size_t)node * 128 + k0 + 4);
            xs[0] = f0.x; xs[1] = f0.y; xs[2] = f0.z; xs[3] = f0.w;
            xs[4] = f1.x; xs[5] = f1.y; xs[6] = f1.z; xs[7] = f1.w;
        }
        f16x8 vh, vl;
#pragma unroll
        for (int i = 0; i < 8; ++i) { f16 hh, ll; split_f(xs[i], hh, ll); vh[i] = hh; vl[i] = ll; }
        f16* dst = &smA[el * SZ + seg * 16];
        *(f16x8*)dst = vh;
        *(f16x8*)(dst + 8) = vl;
    }
    __syncthreads();

    const int lane = t & 63, w = t >> 6, qq = lane >> 4, nn = lane & 15;

    f32x4 acc1[4][2] = {};
    for (int kk = 0; kk < 4; ++kk) {
        f16x8 Ah[4], Al[4];
#pragma unroll
        for (int rt = 0; rt < 4; ++rt) {
            const f16* ap = &smA[(rt * 16 + nn) * SZ + (kk * 4 + qq) * 16];
            Ah[rt] = *(const f16x8*)ap;
            Al[rt] = *(const f16x8*)(ap + 8);
        }
#pragma unroll
        for (int c = 0; c < 2; ++c) {
            const int ct = w * 2 + c;
            const f16* bp = vW1s + (size_t)((ct * 4 + kk) * 2) * 512 + lane * 8;
            const f16x8 Bh = *(const f16x8*)bp;
            const f16x8 Bl = *(const f16x8*)(bp + 512);
#pragma unroll
            for (int rt = 0; rt < 4; ++rt)
                acc1[rt][c] = mfma3(Ah[rt], Al[rt], Bh, Bl, acc1[rt][c]);
        }
    }
#pragma unroll
    for (int c = 0; c < 2; ++c) {
        const int col = w * 32 + c * 16 + nn;
        const float b1 = vb1[col];
#pragma unroll
        for (int rt = 0; rt < 4; ++rt) {
#pragma unroll
            for (int r = 0; r < 4; ++r) {
                const int el = rt * 16 + qq * 4 + r;
                const float z = fmaxf(acc1[rt][c][r] + b1, 0.f);
                f16 zh, zl; split_f(z, zh, zl);
                f16* zp = &smZ[el * SZ + (col >> 3) * 16 + (col & 7)];
                zp[0] = zh; zp[8] = zl;
            }
        }
    }
    __syncthreads();

    float* out_h = out;
    float* out_x = out + (size_t)N_NODES * 128;
    float* out_v = out_x + (size_t)N_NODES * 2;
#pragma unroll
    for (int it = 0; it < 8; ++it) {
        const int idx = it * 256 + t;
        const int rl = idx >> 5, seg = idx & 31;
        const int node = base + rl;
        if (node < N_NODES) {
            *(float4*)(out_h + (size_t)node * 128 + seg * 4) =
                *(const float4*)(h + (size_t)node * 128 + seg * 4);
        }
    }
    if (t < 128) {
        const int node = base + (t >> 1);
        if (node < N_NODES) out_x[node * 2 + (t & 1)] = x[node * 2 + (t & 1)];
    }
    if (t < 128) {
        const int rl = t >> 1, comp = t & 1;
        const int node = base + rl;
        float s = 0.f;
        if (node < N_NODES) {
            s = vb2[comp];
            for (int k = 0; k < 128; ++k) {
                const f16* zp = &smZ[rl * SZ + (k >> 3) * 16 + (k & 7)];
                const float z = (float)zp[0] + (float)zp[8];
                s += z * vW2[k * 2 + comp];
            }
            const float dn = fmaxf(cnt[node], 1.0f);
            s += scat[node * 2 + comp] / dn;
        }
        const float other = __shfl_xor(s, 1);
        if (node < N_NODES) {
            const float nrm = sqrtf(s * s + other * other);
            out_v[node * 2 + comp] = s / fmaxf(nrm, 1e-12f);
        }
    }
}

extern "C" void kernel_launch(void* const* d_in, const int* in_sizes, int n_in,
                              void* d_out, int out_size, void* d_ws, size_t ws_size,
                              hipStream_t stream) {
    const float* h_in = (const float*)d_in[0];
    const float* x    = (const float*)d_in[1];
    const int*   eidx = (const int*)d_in[2];
    const float* embW = (const float*)d_in[3];
    const float* embb = (const float*)d_in[4];
    const float* eW1  = (const float*)d_in[5];
    const float* eb1  = (const float*)d_in[6];
    const float* eW2  = (const float*)d_in[7];
    const float* eb2  = (const float*)d_in[8];
    const float* nW1  = (const float*)d_in[9];
    const float* nb1  = (const float*)d_in[10];
    const float* nW2  = (const float*)d_in[11];
    const float* nb2  = (const float*)d_in[12];
    const float* vW1  = (const float*)d_in[13];
    const float* vb1  = (const float*)d_in[14];
    const float* vW2  = (const float*)d_in[15];
    const float* vb2  = (const float*)d_in[16];
    const float* cW1  = (const float*)d_in[17];
    const float* cb1  = (const float*)d_in[18];
    const float* cW2  = (const float*)d_in[19];
    const float* cb2  = (const float*)d_in[20];

    char* ws = (char*)d_ws;
    float* cnt  = (float*)(ws);
    float* scat = (float*)(ws + OFF_SCAT);
    float* m_i  = (float*)(ws + OFF_MI);
    float* hcur = (float*)(ws + OFF_H);
    f16* eW1s = (f16*)(ws + OFF_W);
    f16* eW2s = eW1s + 65536;
    f16* nW1s = eW2s + 32768;
    f16* nW2s = nW1s + 65536;
    f16* vW1s = nW2s + 32768;
    f16* cW1s = vW1s + 32768;

    hipMemsetAsync(ws, 0, OFF_MI + MI_BYTES, stream);

    prep_kernel<<<512, 256, 0, stream>>>(eW1, eW2, nW1, nW2, vW1, cW1,
                                         eW1s, eW2s, nW1s, nW2s, vW1s, cW1s);
    cnt_kernel<<<(E_EDGES + 255) / 256, 256, 0, stream>>>(eidx, cnt);
    embed_kernel<<<(N_NODES * 128 + 255) / 256, 256, 0, stream>>>(h_in, embW, embb, hcur);

    // layer 1 (v overwritten next layer -> no coord/scatter)
    edge_kernel<<<E_EDGES / 64, 256, 0, stream>>>(eidx, x, hcur,
        eW1s, eW1, eb1, eW2s, eb2, cW1s, cb1, cW2, cb2, m_i, scat, 0);
    node_kernel<<<(N_NODES + 63) / 64, 256, 0, stream>>>(hcur, m_i,
        nW1s, nb1, nW2s, nb2);

    hipMemsetAsync(m_i, 0, MI_BYTES, stream);

    // layer 2 (with coord + scatter)
    edge_kernel<<<E_EDGES / 64, 256, 0, stream>>>(eidx, x, hcur,
        eW1s, eW1, eb1, eW2s, eb2, cW1s, cb1, cW2, cb2, m_i, scat, 1);
    node_kernel<<<(N_NODES + 63) / 64, 256, 0, stream>>>(hcur, m_i,
        nW1s, nb1, nW2s, nb2);

    final_kernel<<<(N_NODES + 63) / 64, 256, 0, stream>>>(hcur, x,
        vW1s, vb1, vW2, vb2, scat, cnt, (float*)d_out);
}

// Round 3
// 1056.369 us; speedup vs baseline: 1.3577x; 1.3577x over previous
//
#include <hip/hip_runtime.h>

typedef unsigned short u16;
typedef _Float16 f16;
typedef f16 f16x8 __attribute__((ext_vector_type(8)));
typedef float f32x4 __attribute__((ext_vector_type(4)));

constexpr int N_NODES = 50000;
constexpr int E_EDGES = 800000;

// workspace layout (bytes)
constexpr size_t OFF_SCAT = 200704;                       // N*2*4
constexpr size_t OFF_MI   = 601088;                       // N*128*4
constexpr size_t MI_BYTES = (size_t)N_NODES * 128 * 4;    // 25,600,000
constexpr size_t OFF_H    = OFF_MI + MI_BYTES;            // h f32
constexpr size_t OFF_W    = OFF_H + MI_BYTES;             // f16 swizzled weights

// f32 -> f16 hi/lo split: x ~= hi + lo, |err| <= 2^-22 |x|
__device__ __forceinline__ void split_f(float x, f16& h, f16& l) {
    h = (f16)x;
    l = (f16)(x - (float)h);
}

__device__ __forceinline__ f32x4 mfma3(f16x8 ah, f16x8 al, f16x8 bh, f16x8 bl, f32x4 acc) {
    acc = __builtin_amdgcn_mfma_f32_16x16x32_f16(ah, bh, acc, 0, 0, 0);
    acc = __builtin_amdgcn_mfma_f32_16x16x32_f16(al, bh, acc, 0, 0, 0);
    acc = __builtin_amdgcn_mfma_f32_16x16x32_f16(ah, bl, acc, 0, 0, 0);
    return acc;
}

// ---- prep: swizzle weights into fragment-order hi/lo f16 planes ----
// flat = (((ct*K32 + kk)*2 + plane)*64 + lane)*8 + j
// col = ct*16 + (lane&15), k = kk*32 + (lane>>4)*8 + j
__global__ __launch_bounds__(256) void prep_kernel(
    const float* __restrict__ eW1, const float* __restrict__ eW2,
    const float* __restrict__ nW1, const float* __restrict__ nW2,
    const float* __restrict__ vW1, const float* __restrict__ cW1,
    f16* __restrict__ eW1s, f16* __restrict__ eW2s,
    f16* __restrict__ nW1s, f16* __restrict__ nW2s,
    f16* __restrict__ vW1s, f16* __restrict__ cW1s)
{
    const int gid = blockIdx.x * 256 + threadIdx.x;   // 131072 total
    const float* W; f16* out; int K32; int e;
    if (gid < 32768)       { W = eW1; out = eW1s; K32 = 8; e = gid; }
    else if (gid < 49152)  { W = eW2; out = eW2s; K32 = 4; e = gid - 32768; }
    else if (gid < 81920)  { W = nW1; out = nW1s; K32 = 8; e = gid - 49152; }
    else if (gid < 98304)  { W = nW2; out = nW2s; K32 = 4; e = gid - 81920; }
    else if (gid < 114688) { W = vW1; out = vW1s; K32 = 4; e = gid - 98304; }
    else                   { W = cW1; out = cW1s; K32 = 4; e = gid - 114688; }
    const int per = 512 * K32;
    const int ct = e / per, rem = e % per;
    const int kk = rem >> 9, lane = (rem >> 3) & 63, j = rem & 7;
    const int col = ct * 16 + (lane & 15);
    const int k = kk * 32 + ((lane >> 4) & 3) * 8 + j;
    const float v = W[k * 128 + col];
    f16 h, l; split_f(v, h, l);
    const int base = ((ct * K32 + kk) * 2) * 512 + lane * 8 + j;
    out[base] = h;
    out[base + 512] = l;
}

// ---- degree count ----
__global__ __launch_bounds__(256) void cnt_kernel(const int* __restrict__ eidx,
                                                  float* __restrict__ cnt) {
    const int e = blockIdx.x * 256 + threadIdx.x;
    if (e < E_EDGES) atomicAdd(&cnt[eidx[e]], 1.0f);
}

// ---- embedding (f32 VALU, tiny) ----
__global__ __launch_bounds__(256) void embed_kernel(
    const float* __restrict__ h_in, const float* __restrict__ embW,
    const float* __restrict__ embb, float* __restrict__ h)
{
    const int gid = blockIdx.x * 256 + threadIdx.x;
    if (gid >= N_NODES * 128) return;
    const int n = gid >> 7, j = gid & 127;
    float s = embb[j];
#pragma unroll
    for (int p = 0; p < 16; ++p) s += h_in[n * 16 + p] * embW[p * 128 + j];
    h[gid] = s;
}

// shared staging helper: split 8 f32 into hi/lo octet pair at dst
__device__ __forceinline__ void stage8(const float* src, f16* dst) {
    const float4 f0 = *(const float4*)src;
    const float4 f1 = *(const float4*)(src + 4);
    const float xs[8] = {f0.x, f0.y, f0.z, f0.w, f1.x, f1.y, f1.z, f1.w};
    f16x8 vh, vl;
#pragma unroll
    for (int i = 0; i < 8; ++i) { f16 hh, ll; split_f(xs[i], hh, ll); vh[i] = hh; vl[i] = ll; }
    *(f16x8*)dst = vh;
    *(f16x8*)(dst + 8) = vl;
}

// ---- edge kernel: m_ij MLP (hi/lo f16) + atomic segment-sum (+ coord & scatter) ----
// LDS ~36 KB -> 4 blocks/CU; K=256 staged in two K=128 chunks; z,m alias smA.
__global__ __launch_bounds__(256, 4) void edge_kernel(
    const int* __restrict__ eidx, const float* __restrict__ x,
    const float* __restrict__ h,
    const f16* __restrict__ eW1s, const float* __restrict__ eW1,
    const float* __restrict__ eb1,
    const f16* __restrict__ eW2s, const float* __restrict__ eb2,
    const f16* __restrict__ cW1s, const float* __restrict__ cb1,
    const float* __restrict__ cW2, const float* __restrict__ cb2,
    float* __restrict__ m_i, float* __restrict__ scat, const int do_coord)
{
    constexpr int S = 264;            // 528 B row stride (4 mod 32 dword banks)
    __shared__ f16 smA[64 * S];       // 33.8 KB: A-chunk, then z, then m (aliased)
    __shared__ int smRow[64];
    __shared__ float smRd[64], smP2x[64], smP2y[64];
    __shared__ float smPart[4][64];

    const int t = threadIdx.x;
    const int base = blockIdx.x * 64;
    const int lane = t & 63, w = t >> 6, qq = lane >> 4, nn = lane & 15;

    if (t < 64) {
        const int e = base + t;
        const int r = eidx[e], c = eidx[E_EDGES + e];
        smRow[t] = r;
        const float dx = x[2 * r] - x[2 * c];
        const float dy = x[2 * r + 1] - x[2 * c + 1];
        smRd[t] = dx * dx + dy * dy;
        smP2x[t] = dx * dx - dy * dy;     // rel_dist*cos(2θ) exactly
        smP2y[t] = 2.0f * dx * dy;        // rel_dist*sin(2θ) exactly
    }

    // ---- GEMM1: z = relu([h_row|h_col] @ eW1 + eb1), K=256 in 2 chunks ----
    f32x4 acc1[4][2] = {};
    for (int chunk = 0; chunk < 2; ++chunk) {
        if (chunk) __syncthreads();   // protect smA until all MFMA reads done
#pragma unroll
        for (int it = 0; it < 4; ++it) {
            const int idx = it * 256 + t;            // 64 edges x 16 octets
            const int el = idx >> 4, seg = idx & 15;
            const int e = base + el;
            const int node = chunk == 0 ? eidx[e] : eidx[E_EDGES + e];
            stage8(h + (size_t)node * 128 + seg * 8, &smA[el * S + seg * 16]);
        }
        __syncthreads();
        for (int kk = 0; kk < 4; ++kk) {
            f16x8 Ah[4], Al[4];
#pragma unroll
            for (int rt = 0; rt < 4; ++rt) {
                const f16* ap = &smA[(rt * 16 + nn) * S + (kk * 4 + qq) * 16];
                Ah[rt] = *(const f16x8*)ap;
                Al[rt] = *(const f16x8*)(ap + 8);
            }
            const int kkg = chunk * 4 + kk;
#pragma unroll
            for (int c = 0; c < 2; ++c) {
                const int ct = w * 2 + c;
                const f16* bp = eW1s + (size_t)((ct * 8 + kkg) * 2) * 512 + lane * 8;
                const f16x8 Bh = *(const f16x8*)bp;
                const f16x8 Bl = *(const f16x8*)(bp + 512);
#pragma unroll
                for (int rt = 0; rt < 4; ++rt)
                    acc1[rt][c] = mfma3(Ah[rt], Al[rt], Bh, Bl, acc1[rt][c]);
            }
        }
    }
    __syncthreads();                  // all reads of chunk1 done -> z may overwrite
#pragma unroll
    for (int c = 0; c < 2; ++c) {
        const int col = w * 32 + c * 16 + nn;
        const float b1 = eb1[col];
        const float wl = eW1[256 * 128 + col];
#pragma unroll
        for (int rt = 0; rt < 4; ++rt) {
#pragma unroll
            for (int r = 0; r < 4; ++r) {
                const int el = rt * 16 + qq * 4 + r;
                const float z = fmaxf(acc1[rt][c][r] + b1 + smRd[el] * wl, 0.f);
                f16 zh, zl; split_f(z, zh, zl);
                f16* zp = &smA[el * S + (col >> 3) * 16 + (col & 7)];
                zp[0] = zh; zp[8] = zl;
            }
        }
    }
    __syncthreads();

    // ---- GEMM2: m = z @ eW2 + eb2, K=128; atomic scatter into m_i ----
    f32x4 acc2[4][2] = {};
    for (int kk = 0; kk < 4; ++kk) {
        f16x8 Ah[4], Al[4];
#pragma unroll
        for (int rt = 0; rt < 4; ++rt) {
            const f16* ap = &smA[(rt * 16 + nn) * S + (kk * 4 + qq) * 16];
            Ah[rt] = *(const f16x8*)ap;
            Al[rt] = *(const f16x8*)(ap + 8);
        }
#pragma unroll
        for (int c = 0; c < 2; ++c) {
            const int ct = w * 2 + c;
            const f16* bp = eW2s + (size_t)((ct * 4 + kk) * 2) * 512 + lane * 8;
            const f16x8 Bh = *(const f16x8*)bp;
            const f16x8 Bl = *(const f16x8*)(bp + 512);
#pragma unroll
            for (int rt = 0; rt < 4; ++rt)
                acc2[rt][c] = mfma3(Ah[rt], Al[rt], Bh, Bl, acc2[rt][c]);
        }
    }
    if (do_coord) __syncthreads();    // all reads of z done -> m may overwrite
#pragma unroll
    for (int c = 0; c < 2; ++c) {
        const int col = w * 32 + c * 16 + nn;
        const float b2 = eb2[col];
#pragma unroll
        for (int rt = 0; rt < 4; ++rt) {
#pragma unroll
            for (int r = 0; r < 4; ++r) {
                const int el = rt * 16 + qq * 4 + r;
                const float mv = acc2[rt][c][r] + b2;
                atomicAdd(&m_i[(size_t)smRow[el] * 128 + col], mv);
                if (do_coord) {
                    f16 mh, ml; split_f(mv, mh, ml);
                    f16* mp = &smA[el * S + (col >> 3) * 16 + (col & 7)];
                    mp[0] = mh; mp[8] = ml;
                }
            }
        }
    }

    if (do_coord) {
        __syncthreads();
        // ---- GEMM3: co = relu(m @ cW1 + cb1) @ cW2 + cb2 ; scatter rel_pos2*co ----
        f32x4 acc3[4][2] = {};
        for (int kk = 0; kk < 4; ++kk) {
            f16x8 Ah[4], Al[4];
#pragma unroll
            for (int rt = 0; rt < 4; ++rt) {
                const f16* ap = &smA[(rt * 16 + nn) * S + (kk * 4 + qq) * 16];
                Ah[rt] = *(const f16x8*)ap;
                Al[rt] = *(const f16x8*)(ap + 8);
            }
#pragma unroll
            for (int c = 0; c < 2; ++c) {
                const int ct = w * 2 + c;
                const f16* bp = cW1s + (size_t)((ct * 4 + kk) * 2) * 512 + lane * 8;
                const f16x8 Bh = *(const f16x8*)bp;
                const f16x8 Bl = *(const f16x8*)(bp + 512);
#pragma unroll
                for (int rt = 0; rt < 4; ++rt)
                    acc3[rt][c] = mfma3(Ah[rt], Al[rt], Bh, Bl, acc3[rt][c]);
            }
        }
        float p3[4][4];
#pragma unroll
        for (int rt = 0; rt < 4; ++rt)
#pragma unroll
            for (int r = 0; r < 4; ++r) p3[rt][r] = 0.f;
#pragma unroll
        for (int c = 0; c < 2; ++c) {
            const int col = w * 32 + c * 16 + nn;
            const float c1 = cb1[col];
            const float w2 = cW2[col];
#pragma unroll
            for (int rt = 0; rt < 4; ++rt)
#pragma unroll
                for (int r = 0; r < 4; ++r)
                    p3[rt][r] += fmaxf(acc3[rt][c][r] + c1, 0.f) * w2;
        }
#pragma unroll
        for (int off = 1; off < 16; off <<= 1)
#pragma unroll
            for (int rt = 0; rt < 4; ++rt)
#pragma unroll
                for (int r = 0; r < 4; ++r) p3[rt][r] += __shfl_xor(p3[rt][r], off);
        if (nn == 0) {
#pragma unroll
            for (int rt = 0; rt < 4; ++rt)
#pragma unroll
                for (int r = 0; r < 4; ++r)
                    smPart[w][rt * 16 + qq * 4 + r] = p3[rt][r];
        }
        __syncthreads();
        if (t < 64) {
            const float co = smPart[0][t] + smPart[1][t] + smPart[2][t] + smPart[3][t] + cb2[0];
            const int rw = smRow[t];
            atomicAdd(&scat[2 * rw],     smP2x[t] * co);
            atomicAdd(&scat[2 * rw + 1], smP2y[t] * co);
        }
    }
}

// ---- node kernel: h += MLP([h, m_i]) — same chunked/aliased structure ----
__global__ __launch_bounds__(256, 4) void node_kernel(
    float* __restrict__ h, const float* __restrict__ m_i,
    const f16* __restrict__ nW1s, const float* __restrict__ nb1,
    const f16* __restrict__ nW2s, const float* __restrict__ nb2)
{
    constexpr int S = 264;
    __shared__ f16 smA[64 * S];
    const int t = threadIdx.x;
    const int base = blockIdx.x * 64;
    const int lane = t & 63, w = t >> 6, qq = lane >> 4, nn = lane & 15;

    f32x4 acc1[4][2] = {};
    for (int chunk = 0; chunk < 2; ++chunk) {
        if (chunk) __syncthreads();
        const float* src0 = chunk == 0 ? h : m_i;
#pragma unroll
        for (int it = 0; it < 4; ++it) {
            const int idx = it * 256 + t;
            const int el = idx >> 4, seg = idx & 15;
            const int node = base + el;
            f16* dst = &smA[el * S + seg * 16];
            if (node < N_NODES) {
                stage8(src0 + (size_t)node * 128 + seg * 8, dst);
            } else {
                *(f16x8*)dst = (f16x8)(f16)0.f;
                *(f16x8*)(dst + 8) = (f16x8)(f16)0.f;
            }
        }
        __syncthreads();
        for (int kk = 0; kk < 4; ++kk) {
            f16x8 Ah[4], Al[4];
#pragma unroll
            for (int rt = 0; rt < 4; ++rt) {
                const f16* ap = &smA[(rt * 16 + nn) * S + (kk * 4 + qq) * 16];
                Ah[rt] = *(const f16x8*)ap;
                Al[rt] = *(const f16x8*)(ap + 8);
            }
            const int kkg = chunk * 4 + kk;
#pragma unroll
            for (int c = 0; c < 2; ++c) {
                const int ct = w * 2 + c;
                const f16* bp = nW1s + (size_t)((ct * 8 + kkg) * 2) * 512 + lane * 8;
                const f16x8 Bh = *(const f16x8*)bp;
                const f16x8 Bl = *(const f16x8*)(bp + 512);
#pragma unroll
                for (int rt = 0; rt < 4; ++rt)
                    acc1[rt][c] = mfma3(Ah[rt], Al[rt], Bh, Bl, acc1[rt][c]);
            }
        }
    }
    __syncthreads();
#pragma unroll
    for (int c = 0; c < 2; ++c) {
        const int col = w * 32 + c * 16 + nn;
        const float b1 = nb1[col];
#pragma unroll
        for (int rt = 0; rt < 4; ++rt) {
#pragma unroll
            for (int r = 0; r < 4; ++r) {
                const int el = rt * 16 + qq * 4 + r;
                const float z = fmaxf(acc1[rt][c][r] + b1, 0.f);
                f16 zh, zl; split_f(z, zh, zl);
                f16* zp = &smA[el * S + (col >> 3) * 16 + (col & 7)];
                zp[0] = zh; zp[8] = zl;
            }
        }
    }
    __syncthreads();

    f32x4 acc2[4][2] = {};
    for (int kk = 0; kk < 4; ++kk) {
        f16x8 Ah[4], Al[4];
#pragma unroll
        for (int rt = 0; rt < 4; ++rt) {
            const f16* ap = &smA[(rt * 16 + nn) * S + (kk * 4 + qq) * 16];
            Ah[rt] = *(const f16x8*)ap;
            Al[rt] = *(const f16x8*)(ap + 8);
        }
#pragma unroll
        for (int c = 0; c < 2; ++c) {
            const int ct = w * 2 + c;
            const f16* bp = nW2s + (size_t)((ct * 4 + kk) * 2) * 512 + lane * 8;
            const f16x8 Bh = *(const f16x8*)bp;
            const f16x8 Bl = *(const f16x8*)(bp + 512);
#pragma unroll
            for (int rt = 0; rt < 4; ++rt)
                acc2[rt][c] = mfma3(Ah[rt], Al[rt], Bh, Bl, acc2[rt][c]);
        }
    }
#pragma unroll
    for (int c = 0; c < 2; ++c) {
        const int col = w * 32 + c * 16 + nn;
        const float b2 = nb2[col];
#pragma unroll
        for (int rt = 0; rt < 4; ++rt) {
#pragma unroll
            for (int r = 0; r < 4; ++r) {
                const int el = rt * 16 + qq * 4 + r;
                const int node = base + el;
                if (node < N_NODES) {
                    const size_t ix = (size_t)node * 128 + col;
                    h[ix] = h[ix] + acc2[rt][c][r] + b2;
                }
            }
        }
    }
}

// ---- final: v = MLP_v(h) + scat/denom, L2-normalize; write h | x | v ----
__global__ __launch_bounds__(256, 4) void final_kernel(
    const float* __restrict__ h, const float* __restrict__ x,
    const f16* __restrict__ vW1s, const float* __restrict__ vb1,
    const float* __restrict__ vW2, const float* __restrict__ vb2,
    const float* __restrict__ scat, const float* __restrict__ cnt,
    float* __restrict__ out)
{
    constexpr int S = 264;
    __shared__ f16 smA[64 * S];
    const int t = threadIdx.x;
    const int base = blockIdx.x * 64;
    const int lane = t & 63, w = t >> 6, qq = lane >> 4, nn = lane & 15;

#pragma unroll
    for (int it = 0; it < 4; ++it) {
        const int idx = it * 256 + t;
        const int el = idx >> 4, seg = idx & 15;
        const int node = base + el;
        f16* dst = &smA[el * S + seg * 16];
        if (node < N_NODES) {
            stage8(h + (size_t)node * 128 + seg * 8, dst);
        } else {
            *(f16x8*)dst = (f16x8)(f16)0.f;
            *(f16x8*)(dst + 8) = (f16x8)(f16)0.f;
        }
    }
    __syncthreads();

    f32x4 acc1[4][2] = {};
    for (int kk = 0; kk < 4; ++kk) {
        f16x8 Ah[4], Al[4];
#pragma unroll
        for (int rt = 0; rt < 4; ++rt) {
            const f16* ap = &smA[(rt * 16 + nn) * S + (kk * 4 + qq) * 16];
            Ah[rt] = *(const f16x8*)ap;
            Al[rt] = *(const f16x8*)(ap + 8);
        }
#pragma unroll
        for (int c = 0; c < 2; ++c) {
            const int ct = w * 2 + c;
            const f16* bp = vW1s + (size_t)((ct * 4 + kk) * 2) * 512 + lane * 8;
            const f16x8 Bh = *(const f16x8*)bp;
            const f16x8 Bl = *(const f16x8*)(bp + 512);
#pragma unroll
            for (int rt = 0; rt < 4; ++rt)
                acc1[rt][c] = mfma3(Ah[rt], Al[rt], Bh, Bl, acc1[rt][c]);
        }
    }
    __syncthreads();
#pragma unroll
    for (int c = 0; c < 2; ++c) {
        const int col = w * 32 + c * 16 + nn;
        const float b1 = vb1[col];
#pragma unroll
        for (int rt = 0; rt < 4; ++rt) {
#pragma unroll
            for (int r = 0; r < 4; ++r) {
                const int el = rt * 16 + qq * 4 + r;
                const float z = fmaxf(acc1[rt][c][r] + b1, 0.f);
                f16 zh, zl; split_f(z, zh, zl);
                f16* zp = &smA[el * S + (col >> 3) * 16 + (col & 7)];
                zp[0] = zh; zp[8] = zl;
            }
        }
    }
    __syncthreads();

    float* out_h = out;
    float* out_x = out + (size_t)N_NODES * 128;
    float* out_v = out_x + (size_t)N_NODES * 2;
#pragma unroll
    for (int it = 0; it < 8; ++it) {
        const int idx = it * 256 + t;
        const int rl = idx >> 5, seg = idx & 31;
        const int node = base + rl;
        if (node < N_NODES) {
            *(float4*)(out_h + (size_t)node * 128 + seg * 4) =
                *(const float4*)(h + (size_t)node * 128 + seg * 4);
        }
    }
    if (t < 128) {
        const int node = base + (t >> 1);
        if (node < N_NODES) out_x[node * 2 + (t & 1)] = x[node * 2 + (t & 1)];
    }
    if (t < 128) {
        const int rl = t >> 1, comp = t & 1;
        const int node = base + rl;
        float s = 0.f;
        if (node < N_NODES) {
            s = vb2[comp];
            for (int k = 0; k < 128; ++k) {
                const f16* zp = &smA[rl * S + (k >> 3) * 16 + (k & 7)];
                const float z = (float)zp[0] + (float)zp[8];
                s += z * vW2[k * 2 + comp];
            }
            const float dn = fmaxf(cnt[node], 1.0f);
            s += scat[node * 2 + comp] / dn;
        }
        const float other = __shfl_xor(s, 1);
        if (node < N_NODES) {
            const float nrm = sqrtf(s * s + other * other);
            out_v[node * 2 + comp] = s / fmaxf(nrm, 1e-12f);
        }
    }
}

extern "C" void kernel_launch(void* const* d_in, const int* in_sizes, int n_in,
                              void* d_out, int out_size, void* d_ws, size_t ws_size,
                              hipStream_t stream) {
    const float* h_in = (const float*)d_in[0];
    const float* x    = (const float*)d_in[1];
    const int*   eidx = (const int*)d_in[2];
    const float* embW = (const float*)d_in[3];
    const float* embb = (const float*)d_in[4];
    const float* eW1  = (const float*)d_in[5];
    const float* eb1  = (const float*)d_in[6];
    const float* eW2  = (const float*)d_in[7];
    const float* eb2  = (const float*)d_in[8];
    const float* nW1  = (const float*)d_in[9];
    const float* nb1  = (const float*)d_in[10];
    const float* nW2  = (const float*)d_in[11];
    const float* nb2  = (const float*)d_in[12];
    const float* vW1  = (const float*)d_in[13];
    const float* vb1  = (const float*)d_in[14];
    const float* vW2  = (const float*)d_in[15];
    const float* vb2  = (const float*)d_in[16];
    const float* cW1  = (const float*)d_in[17];
    const float* cb1  = (const float*)d_in[18];
    const float* cW2  = (const float*)d_in[19];
    const float* cb2  = (const float*)d_in[20];

    char* ws = (char*)d_ws;
    float* cnt  = (float*)(ws);
    float* scat = (float*)(ws + OFF_SCAT);
    float* m_i  = (float*)(ws + OFF_MI);
    float* hcur = (float*)(ws + OFF_H);
    f16* eW1s = (f16*)(ws + OFF_W);
    f16* eW2s = eW1s + 65536;
    f16* nW1s = eW2s + 32768;
    f16* nW2s = nW1s + 65536;
    f16* vW1s = nW2s + 32768;
    f16* cW1s = vW1s + 32768;

    hipMemsetAsync(ws, 0, OFF_MI + MI_BYTES, stream);

    prep_kernel<<<512, 256, 0, stream>>>(eW1, eW2, nW1, nW2, vW1, cW1,
                                         eW1s, eW2s, nW1s, nW2s, vW1s, cW1s);
    cnt_kernel<<<(E_EDGES + 255) / 256, 256, 0, stream>>>(eidx, cnt);
    embed_kernel<<<(N_NODES * 128 + 255) / 256, 256, 0, stream>>>(h_in, embW, embb, hcur);

    // layer 1 (v overwritten next layer -> no coord/scatter)
    edge_kernel<<<E_EDGES / 64, 256, 0, stream>>>(eidx, x, hcur,
        eW1s, eW1, eb1, eW2s, eb2, cW1s, cb1, cW2, cb2, m_i, scat, 0);
    node_kernel<<<(N_NODES + 63) / 64, 256, 0, stream>>>(hcur, m_i,
        nW1s, nb1, nW2s, nb2);

    hipMemsetAsync(m_i, 0, MI_BYTES, stream);

    // layer 2 (with coord + scatter)
    edge_kernel<<<E_EDGES / 64, 256, 0, stream>>>(eidx, x, hcur,
        eW1s, eW1, eb1, eW2s, eb2, cW1s, cb1, cW2, cb2, m_i, scat, 1);
    node_kernel<<<(N_NODES + 63) / 64, 256, 0, stream>>>(hcur, m_i,
        nW1s, nb1, nW2s, nb2);

    final_kernel<<<(N_NODES + 63) / 64, 256, 0, stream>>>(hcur, x,
        vW1s, vb1, vW2, vb2, scat, cnt, (float*)d_out);
}

// Round 4
// 1040.867 us; speedup vs baseline: 1.3779x; 1.0149x over previous
//
#include <hip/hip_runtime.h>

typedef unsigned short u16;
typedef _Float16 f16;
typedef f16 f16x8 __attribute__((ext_vector_type(8)));
typedef float f32x4 __attribute__((ext_vector_type(4)));

constexpr int N_NODES = 50000;
constexpr int E_EDGES = 800000;
constexpr int NBINS   = 50176;            // 196 * 256
constexpr int NBLK    = 196;

// workspace layout (bytes)
constexpr size_t OFF_DEG   = 0;           // NBINS*4
constexpr size_t OFF_LOCEX = 200704;      // NBINS*4
constexpr size_t OFF_BSUM  = 401408;      // 1024
constexpr size_t OFF_BOFF  = 402432;      // 1024
constexpr size_t OFF_FILL  = 403456;      // NBINS*4
constexpr size_t OFF_SCAT  = 604160;      // N*2*4
constexpr size_t OFF_SROW  = 1004160;     // E*4
constexpr size_t OFF_SCOL  = 4204160;     // E*4
constexpr size_t OFF_MI    = 7404160;     // N*128*4
constexpr size_t MI_BYTES  = (size_t)N_NODES * 128 * 4;
constexpr size_t OFF_H     = OFF_MI + MI_BYTES;
constexpr size_t OFF_W     = OFF_H + MI_BYTES;

// f32 -> f16 hi/lo split: x ~= hi + lo, |err| <= 2^-22 |x|
__device__ __forceinline__ void split_f(float x, f16& h, f16& l) {
    h = (f16)x;
    l = (f16)(x - (float)h);
}

__device__ __forceinline__ f32x4 mfma3(f16x8 ah, f16x8 al, f16x8 bh, f16x8 bl, f32x4 acc) {
    acc = __builtin_amdgcn_mfma_f32_16x16x32_f16(ah, bh, acc, 0, 0, 0);
    acc = __builtin_amdgcn_mfma_f32_16x16x32_f16(al, bh, acc, 0, 0, 0);
    acc = __builtin_amdgcn_mfma_f32_16x16x32_f16(ah, bl, acc, 0, 0, 0);
    return acc;
}

// ---- prep: swizzle weights into fragment-order hi/lo f16 planes ----
__global__ __launch_bounds__(256) void prep_kernel(
    const float* __restrict__ eW1, const float* __restrict__ eW2,
    const float* __restrict__ nW1, const float* __restrict__ nW2,
    const float* __restrict__ vW1, const float* __restrict__ cW1,
    f16* __restrict__ eW1s, f16* __restrict__ eW2s,
    f16* __restrict__ nW1s, f16* __restrict__ nW2s,
    f16* __restrict__ vW1s, f16* __restrict__ cW1s)
{
    const int gid = blockIdx.x * 256 + threadIdx.x;   // 131072 total
    const float* W; f16* out; int K32; int e;
    if (gid < 32768)       { W = eW1; out = eW1s; K32 = 8; e = gid; }
    else if (gid < 49152)  { W = eW2; out = eW2s; K32 = 4; e = gid - 32768; }
    else if (gid < 81920)  { W = nW1; out = nW1s; K32 = 8; e = gid - 49152; }
    else if (gid < 98304)  { W = nW2; out = nW2s; K32 = 4; e = gid - 81920; }
    else if (gid < 114688) { W = vW1; out = vW1s; K32 = 4; e = gid - 98304; }
    else                   { W = cW1; out = cW1s; K32 = 4; e = gid - 114688; }
    const int per = 512 * K32;
    const int ct = e / per, rem = e % per;
    const int kk = rem >> 9, lane = (rem >> 3) & 63, j = rem & 7;
    const int col = ct * 16 + (lane & 15);
    const int k = kk * 32 + ((lane >> 4) & 3) * 8 + j;
    const float v = W[k * 128 + col];
    f16 h, l; split_f(v, h, l);
    const int base = ((ct * K32 + kk) * 2) * 512 + lane * 8 + j;
    out[base] = h;
    out[base + 512] = l;
}

// ---- sort pipeline: counting sort of edges by source row ----
__global__ __launch_bounds__(256) void hist_kernel(const int* __restrict__ eidx,
                                                   int* __restrict__ deg) {
    const int e = blockIdx.x * 256 + threadIdx.x;
    if (e < E_EDGES) atomicAdd(&deg[eidx[e]], 1);
}

__global__ __launch_bounds__(256) void scan1_kernel(const int* __restrict__ deg,
                                                    int* __restrict__ locEx,
                                                    int* __restrict__ blockSum) {
    __shared__ int s[256];
    const int t = threadIdx.x;
    const int gid = blockIdx.x * 256 + t;
    const int v = deg[gid];
    s[t] = v;
    __syncthreads();
    for (int off = 1; off < 256; off <<= 1) {
        const int add = (t >= off) ? s[t - off] : 0;
        __syncthreads();
        s[t] += add;
        __syncthreads();
    }
    locEx[gid] = s[t] - v;
    if (t == 255) blockSum[blockIdx.x] = s[255];
}

__global__ __launch_bounds__(256) void scan2_kernel(const int* __restrict__ blockSum,
                                                    int* __restrict__ blockOff) {
    __shared__ int s[256];
    const int t = threadIdx.x;
    const int v = (t < NBLK) ? blockSum[t] : 0;
    s[t] = v;
    __syncthreads();
    for (int off = 1; off < 256; off <<= 1) {
        const int add = (t >= off) ? s[t - off] : 0;
        __syncthreads();
        s[t] += add;
        __syncthreads();
    }
    if (t < NBLK) blockOff[t] = s[t] - v;
}

__global__ __launch_bounds__(256) void scatter_kernel(const int* __restrict__ eidx,
        const int* __restrict__ locEx, const int* __restrict__ blockOff,
        int* __restrict__ fill, int* __restrict__ srow, int* __restrict__ scol) {
    const int e = blockIdx.x * 256 + threadIdx.x;
    if (e >= E_EDGES) return;
    const int r = eidx[e], c = eidx[E_EDGES + e];
    const int pos = blockOff[r >> 8] + locEx[r] + atomicAdd(&fill[r], 1);
    srow[pos] = r;
    scol[pos] = c;
}

// ---- embedding (f32 VALU, tiny) ----
__global__ __launch_bounds__(256) void embed_kernel(
    const float* __restrict__ h_in, const float* __restrict__ embW,
    const float* __restrict__ embb, float* __restrict__ h)
{
    const int gid = blockIdx.x * 256 + threadIdx.x;
    if (gid >= N_NODES * 128) return;
    const int n = gid >> 7, j = gid & 127;
    float s = embb[j];
#pragma unroll
    for (int p = 0; p < 16; ++p) s += h_in[n * 16 + p] * embW[p * 128 + j];
    h[gid] = s;
}

// staging helpers: split 8 f32 into hi/lo octet pair at dst
__device__ __forceinline__ void stage8(const float* src, f16* dst) {
    const float4 f0 = *(const float4*)src;
    const float4 f1 = *(const float4*)(src + 4);
    const float xs[8] = {f0.x, f0.y, f0.z, f0.w, f1.x, f1.y, f1.z, f1.w};
    f16x8 vh, vl;
#pragma unroll
    for (int i = 0; i < 8; ++i) { f16 hh, ll; split_f(xs[i], hh, ll); vh[i] = hh; vl[i] = ll; }
    *(f16x8*)dst = vh;
    *(f16x8*)(dst + 8) = vl;
}
__device__ __forceinline__ void stage8v(float4 f0, float4 f1, f16* dst) {
    const float xs[8] = {f0.x, f0.y, f0.z, f0.w, f1.x, f1.y, f1.z, f1.w};
    f16x8 vh, vl;
#pragma unroll
    for (int i = 0; i < 8; ++i) { f16 hh, ll; split_f(xs[i], hh, ll); vh[i] = hh; vl[i] = ll; }
    *(f16x8*)dst = vh;
    *(f16x8*)(dst + 8) = vl;
}

// ---- edge kernel: sorted edges; m_ij MLP + run-merged segment-sum (+ coord) ----
__global__ __launch_bounds__(256, 4) void edge_kernel(
    const int* __restrict__ srow, const int* __restrict__ scol,
    const float* __restrict__ x, const float* __restrict__ h,
    const f16* __restrict__ eW1s, const float* __restrict__ eW1,
    const float* __restrict__ eb1,
    const f16* __restrict__ eW2s, const float* __restrict__ eb2,
    const f16* __restrict__ cW1s, const float* __restrict__ cb1,
    const float* __restrict__ cW2, const float* __restrict__ cb2,
    float* __restrict__ m_i, float* __restrict__ scat, const int do_coord)
{
    constexpr int S = 264;            // 528 B row stride
    __shared__ f16 smA[64 * S];       // 33.8 KB: A-chunk -> z -> m (aliased)
    __shared__ int smRow[64];
    __shared__ float smRd[64], smP2x[64], smP2y[64];
    __shared__ float smPart[4][64];

    const int t = threadIdx.x;
    const int base = blockIdx.x * 64;
    const int lane = t & 63, w = t >> 6, qq = lane >> 4, nn = lane & 15;

    // prefetch the h[col] gather (long-latency) into registers
    float4 p0[4], p1[4];
#pragma unroll
    for (int it = 0; it < 4; ++it) {
        const int idx = it * 256 + t;
        const int el = idx >> 4, seg = idx & 15;
        const int node = scol[base + el];
        const float* src = h + (size_t)node * 128 + seg * 8;
        p0[it] = *(const float4*)src;
        p1[it] = *(const float4*)(src + 4);
    }
    if (t < 64) {
        const int e = base + t;
        const int r = srow[e], c = scol[e];
        smRow[t] = r;
        const float dx = x[2 * r] - x[2 * c];
        const float dy = x[2 * r + 1] - x[2 * c + 1];
        smRd[t] = dx * dx + dy * dy;
        smP2x[t] = dx * dx - dy * dy;     // rel_dist*cos(2θ) exactly
        smP2y[t] = 2.0f * dx * dy;        // rel_dist*sin(2θ) exactly
    }
    // stage chunk0 = h[row] (sorted rows -> L1-local)
#pragma unroll
    for (int it = 0; it < 4; ++it) {
        const int idx = it * 256 + t;
        const int el = idx >> 4, seg = idx & 15;
        const int node = srow[base + el];
        stage8(h + (size_t)node * 128 + seg * 8, &smA[el * S + seg * 16]);
    }
    __syncthreads();

    // ---- GEMM1: z = relu([h_row|h_col] @ eW1 + eb1), K=256 in 2 chunks ----
    f32x4 acc1[4][2] = {};
    for (int chunk = 0; chunk < 2; ++chunk) {
        if (chunk) {
            __syncthreads();   // chunk0 reads done
#pragma unroll
            for (int it = 0; it < 4; ++it) {
                const int idx = it * 256 + t;
                const int el = idx >> 4, seg = idx & 15;
                stage8v(p0[it], p1[it], &smA[el * S + seg * 16]);
            }
            __syncthreads();
        }
        for (int kk = 0; kk < 4; ++kk) {
            f16x8 Ah[4], Al[4];
#pragma unroll
            for (int rt = 0; rt < 4; ++rt) {
                const f16* ap = &smA[(rt * 16 + nn) * S + (kk * 4 + qq) * 16];
                Ah[rt] = *(const f16x8*)ap;
                Al[rt] = *(const f16x8*)(ap + 8);
            }
            const int kkg = chunk * 4 + kk;
#pragma unroll
            for (int c = 0; c < 2; ++c) {
                const int ct = w * 2 + c;
                const f16* bp = eW1s + (size_t)((ct * 8 + kkg) * 2) * 512 + lane * 8;
                const f16x8 Bh = *(const f16x8*)bp;
                const f16x8 Bl = *(const f16x8*)(bp + 512);
#pragma unroll
                for (int rt = 0; rt < 4; ++rt)
                    acc1[rt][c] = mfma3(Ah[rt], Al[rt], Bh, Bl, acc1[rt][c]);
            }
        }
    }
    __syncthreads();                  // chunk1 reads done -> z may overwrite
#pragma unroll
    for (int c = 0; c < 2; ++c) {
        const int col = w * 32 + c * 16 + nn;
        const float b1 = eb1[col];
        const float wl = eW1[256 * 128 + col];
#pragma unroll
        for (int rt = 0; rt < 4; ++rt) {
#pragma unroll
            for (int r = 0; r < 4; ++r) {
                const int el = rt * 16 + qq * 4 + r;
                const float z = fmaxf(acc1[rt][c][r] + b1 + smRd[el] * wl, 0.f);
                f16 zh, zl; split_f(z, zh, zl);
                f16* zp = &smA[el * S + (col >> 3) * 16 + (col & 7)];
                zp[0] = zh; zp[8] = zl;
            }
        }
    }
    __syncthreads();

    // ---- GEMM2: m = z @ eW2 + eb2, K=128 ----
    f32x4 acc2[4][2] = {};
    for (int kk = 0; kk < 4; ++kk) {
        f16x8 Ah[4], Al[4];
#pragma unroll
        for (int rt = 0; rt < 4; ++rt) {
            const f16* ap = &smA[(rt * 16 + nn) * S + (kk * 4 + qq) * 16];
            Ah[rt] = *(const f16x8*)ap;
            Al[rt] = *(const f16x8*)(ap + 8);
        }
#pragma unroll
        for (int c = 0; c < 2; ++c) {
            const int ct = w * 2 + c;
            const f16* bp = eW2s + (size_t)((ct * 4 + kk) * 2) * 512 + lane * 8;
            const f16x8 Bh = *(const f16x8*)bp;
            const f16x8 Bl = *(const f16x8*)(bp + 512);
#pragma unroll
            for (int rt = 0; rt < 4; ++rt)
                acc2[rt][c] = mfma3(Ah[rt], Al[rt], Bh, Bl, acc2[rt][c]);
        }
    }
    __syncthreads();                  // z reads done -> m-tile may overwrite
#pragma unroll
    for (int c = 0; c < 2; ++c) {
        const int col = w * 32 + c * 16 + nn;
        const float b2 = eb2[col];
#pragma unroll
        for (int rt = 0; rt < 4; ++rt) {
#pragma unroll
            for (int r = 0; r < 4; ++r) {
                const int el = rt * 16 + qq * 4 + r;
                const float mv = acc2[rt][c][r] + b2;
                f16 mh, ml; split_f(mv, mh, ml);
                f16* mp = &smA[el * S + (col >> 3) * 16 + (col & 7)];
                mp[0] = mh; mp[8] = ml;
            }
        }
    }
    __syncthreads();

    // ---- run-merged segment-sum: rows sorted -> ~1 atomic per row-run ----
    {
        const int col = t & 127;
        const int r0 = (t >> 7) * 32;
        const f16* mpBase = smA + (col >> 3) * 16 + (col & 7);
        float acc = 0.f;
        int prev = smRow[r0];
        for (int el = r0; el < r0 + 32; ++el) {
            const int rw = smRow[el];
            if (rw != prev) {
                atomicAdd(&m_i[(size_t)prev * 128 + col], acc);
                acc = 0.f; prev = rw;
            }
            const f16* mp = mpBase + el * S;
            acc += (float)mp[0] + (float)mp[8];
        }
        atomicAdd(&m_i[(size_t)prev * 128 + col], acc);
    }

    if (do_coord) {
        // ---- GEMM3: co = relu(m @ cW1 + cb1) @ cW2 + cb2 ; scatter rel_pos2*co ----
        f32x4 acc3[4][2] = {};
        for (int kk = 0; kk < 4; ++kk) {
            f16x8 Ah[4], Al[4];
#pragma unroll
            for (int rt = 0; rt < 4; ++rt) {
                const f16* ap = &smA[(rt * 16 + nn) * S + (kk * 4 + qq) * 16];
                Ah[rt] = *(const f16x8*)ap;
                Al[rt] = *(const f16x8*)(ap + 8);
            }
#pragma unroll
            for (int c = 0; c < 2; ++c) {
                const int ct = w * 2 + c;
                const f16* bp = cW1s + (size_t)((ct * 4 + kk) * 2) * 512 + lane * 8;
                const f16x8 Bh = *(const f16x8*)bp;
                const f16x8 Bl = *(const f16x8*)(bp + 512);
#pragma unroll
                for (int rt = 0; rt < 4; ++rt)
                    acc3[rt][c] = mfma3(Ah[rt], Al[rt], Bh, Bl, acc3[rt][c]);
            }
        }
        float p3[4][4];
#pragma unroll
        for (int rt = 0; rt < 4; ++rt)
#pragma unroll
            for (int r = 0; r < 4; ++r) p3[rt][r] = 0.f;
#pragma unroll
        for (int c = 0; c < 2; ++c) {
            const int col = w * 32 + c * 16 + nn;
            const float c1 = cb1[col];
            const float w2 = cW2[col];
#pragma unroll
            for (int rt = 0; rt < 4; ++rt)
#pragma unroll
                for (int r = 0; r < 4; ++r)
                    p3[rt][r] += fmaxf(acc3[rt][c][r] + c1, 0.f) * w2;
        }
#pragma unroll
        for (int off = 1; off < 16; off <<= 1)
#pragma unroll
            for (int rt = 0; rt < 4; ++rt)
#pragma unroll
                for (int r = 0; r < 4; ++r) p3[rt][r] += __shfl_xor(p3[rt][r], off);
        if (nn == 0) {
#pragma unroll
            for (int rt = 0; rt < 4; ++rt)
#pragma unroll
                for (int r = 0; r < 4; ++r)
                    smPart[w][rt * 16 + qq * 4 + r] = p3[rt][r];
        }
        __syncthreads();
        if (t < 64) {
            const float co = smPart[0][t] + smPart[1][t] + smPart[2][t] + smPart[3][t] + cb2[0];
            const int rw = smRow[t];
            atomicAdd(&scat[2 * rw],     smP2x[t] * co);
            atomicAdd(&scat[2 * rw + 1], smP2y[t] * co);
        }
    }
}

// ---- node kernel: h += MLP([h, m_i]) ----
__global__ __launch_bounds__(256, 4) void node_kernel(
    float* __restrict__ h, const float* __restrict__ m_i,
    const f16* __restrict__ nW1s, const float* __restrict__ nb1,
    const f16* __restrict__ nW2s, const float* __restrict__ nb2)
{
    constexpr int S = 264;
    __shared__ f16 smA[64 * S];
    const int t = threadIdx.x;
    const int base = blockIdx.x * 64;
    const int lane = t & 63, w = t >> 6, qq = lane >> 4, nn = lane & 15;

    f32x4 acc1[4][2] = {};
    for (int chunk = 0; chunk < 2; ++chunk) {
        if (chunk) __syncthreads();
        const float* src0 = chunk == 0 ? h : m_i;
#pragma unroll
        for (int it = 0; it < 4; ++it) {
            const int idx = it * 256 + t;
            const int el = idx >> 4, seg = idx & 15;
            const int node = base + el;
            f16* dst = &smA[el * S + seg * 16];
            if (node < N_NODES) {
                stage8(src0 + (size_t)node * 128 + seg * 8, dst);
            } else {
                *(f16x8*)dst = (f16x8)(f16)0.f;
                *(f16x8*)(dst + 8) = (f16x8)(f16)0.f;
            }
        }
        __syncthreads();
        for (int kk = 0; kk < 4; ++kk) {
            f16x8 Ah[4], Al[4];
#pragma unroll
            for (int rt = 0; rt < 4; ++rt) {
                const f16* ap = &smA[(rt * 16 + nn) * S + (kk * 4 + qq) * 16];
                Ah[rt] = *(const f16x8*)ap;
                Al[rt] = *(const f16x8*)(ap + 8);
            }
            const int kkg = chunk * 4 + kk;
#pragma unroll
            for (int c = 0; c < 2; ++c) {
                const int ct = w * 2 + c;
                const f16* bp = nW1s + (size_t)((ct * 8 + kkg) * 2) * 512 + lane * 8;
                const f16x8 Bh = *(const f16x8*)bp;
                const f16x8 Bl = *(const f16x8*)(bp + 512);
#pragma unroll
                for (int rt = 0; rt < 4; ++rt)
                    acc1[rt][c] = mfma3(Ah[rt], Al[rt], Bh, Bl, acc1[rt][c]);
            }
        }
    }
    __syncthreads();
#pragma unroll
    for (int c = 0; c < 2; ++c) {
        const int col = w * 32 + c * 16 + nn;
        const float b1 = nb1[col];
#pragma unroll
        for (int rt = 0; rt < 4; ++rt) {
#pragma unroll
            for (int r = 0; r < 4; ++r) {
                const int el = rt * 16 + qq * 4 + r;
                const float z = fmaxf(acc1[rt][c][r] + b1, 0.f);
                f16 zh, zl; split_f(z, zh, zl);
                f16* zp = &smA[el * S + (col >> 3) * 16 + (col & 7)];
                zp[0] = zh; zp[8] = zl;
            }
        }
    }
    __syncthreads();

    f32x4 acc2[4][2] = {};
    for (int kk = 0; kk < 4; ++kk) {
        f16x8 Ah[4], Al[4];
#pragma unroll
        for (int rt = 0; rt < 4; ++rt) {
            const f16* ap = &smA[(rt * 16 + nn) * S + (kk * 4 + qq) * 16];
            Ah[rt] = *(const f16x8*)ap;
            Al[rt] = *(const f16x8*)(ap + 8);
        }
#pragma unroll
        for (int c = 0; c < 2; ++c) {
            const int ct = w * 2 + c;
            const f16* bp = nW2s + (size_t)((ct * 4 + kk) * 2) * 512 + lane * 8;
            const f16x8 Bh = *(const f16x8*)bp;
            const f16x8 Bl = *(const f16x8*)(bp + 512);
#pragma unroll
            for (int rt = 0; rt < 4; ++rt)
                acc2[rt][c] = mfma3(Ah[rt], Al[rt], Bh, Bl, acc2[rt][c]);
        }
    }
#pragma unroll
    for (int c = 0; c < 2; ++c) {
        const int col = w * 32 + c * 16 + nn;
        const float b2 = nb2[col];
#pragma unroll
        for (int rt = 0; rt < 4; ++rt) {
#pragma unroll
            for (int r = 0; r < 4; ++r) {
                const int el = rt * 16 + qq * 4 + r;
                const int node = base + el;
                if (node < N_NODES) {
                    const size_t ix = (size_t)node * 128 + col;
                    h[ix] = h[ix] + acc2[rt][c][r] + b2;
                }
            }
        }
    }
}

// ---- final: v = MLP_v(h) + scat/denom, L2-normalize; write h | x | v ----
__global__ __launch_bounds__(256, 4) void final_kernel(
    const float* __restrict__ h, const float* __restrict__ x,
    const f16* __restrict__ vW1s, const float* __restrict__ vb1,
    const float* __restrict__ vW2, const float* __restrict__ vb2,
    const float* __restrict__ scat, const int* __restrict__ deg,
    float* __restrict__ out)
{
    constexpr int S = 264;
    __shared__ f16 smA[64 * S];
    const int t = threadIdx.x;
    const int base = blockIdx.x * 64;
    const int lane = t & 63, w = t >> 6, qq = lane >> 4, nn = lane & 15;

#pragma unroll
    for (int it = 0; it < 4; ++it) {
        const int idx = it * 256 + t;
        const int el = idx >> 4, seg = idx & 15;
        const int node = base + el;
        f16* dst = &smA[el * S + seg * 16];
        if (node < N_NODES) {
            stage8(h + (size_t)node * 128 + seg * 8, dst);
        } else {
            *(f16x8*)dst = (f16x8)(f16)0.f;
            *(f16x8*)(dst + 8) = (f16x8)(f16)0.f;
        }
    }
    __syncthreads();

    f32x4 acc1[4][2] = {};
    for (int kk = 0; kk < 4; ++kk) {
        f16x8 Ah[4], Al[4];
#pragma unroll
        for (int rt = 0; rt < 4; ++rt) {
            const f16* ap = &smA[(rt * 16 + nn) * S + (kk * 4 + qq) * 16];
            Ah[rt] = *(const f16x8*)ap;
            Al[rt] = *(const f16x8*)(ap + 8);
        }
#pragma unroll
        for (int c = 0; c < 2; ++c) {
            const int ct = w * 2 + c;
            const f16* bp = vW1s + (size_t)((ct * 4 + kk) * 2) * 512 + lane * 8;
            const f16x8 Bh = *(const f16x8*)bp;
            const f16x8 Bl = *(const f16x8*)(bp + 512);
#pragma unroll
            for (int rt = 0; rt < 4; ++rt)
                acc1[rt][c] = mfma3(Ah[rt], Al[rt], Bh, Bl, acc1[rt][c]);
        }
    }
    __syncthreads();
#pragma unroll
    for (int c = 0; c < 2; ++c) {
        const int col = w * 32 + c * 16 + nn;
        const float b1 = vb1[col];
#pragma unroll
        for (int rt = 0; rt < 4; ++rt) {
#pragma unroll
            for (int r = 0; r < 4; ++r) {
                const int el = rt * 16 + qq * 4 + r;
                const float z = fmaxf(acc1[rt][c][r] + b1, 0.f);
                f16 zh, zl; split_f(z, zh, zl);
                f16* zp = &smA[el * S + (col >> 3) * 16 + (col & 7)];
                zp[0] = zh; zp[8] = zl;
            }
        }
    }
    __syncthreads();

    float* out_h = out;
    float* out_x = out + (size_t)N_NODES * 128;
    float* out_v = out_x + (size_t)N_NODES * 2;
#pragma unroll
    for (int it = 0; it < 8; ++it) {
        const int idx = it * 256 + t;
        const int rl = idx >> 5, seg = idx & 31;
        const int node = base + rl;
        if (node < N_NODES) {
            *(float4*)(out_h + (size_t)node * 128 + seg * 4) =
                *(const float4*)(h + (size_t)node * 128 + seg * 4);
        }
    }
    if (t < 128) {
        const int node = base + (t >> 1);
        if (node < N_NODES) out_x[node * 2 + (t & 1)] = x[node * 2 + (t & 1)];
    }
    if (t < 128) {
        const int rl = t >> 1, comp = t & 1;
        const int node = base + rl;
        float s = 0.f;
        if (node < N_NODES) {
            s = vb2[comp];
            for (int k = 0; k < 128; ++k) {
                const f16* zp = &smA[rl * S + (k >> 3) * 16 + (k & 7)];
                const float z = (float)zp[0] + (float)zp[8];
                s += z * vW2[k * 2 + comp];
            }
            const float dn = fmaxf((float)deg[node], 1.0f);
            s += scat[node * 2 + comp] / dn;
        }
        const float other = __shfl_xor(s, 1);
        if (node < N_NODES) {
            const float nrm = sqrtf(s * s + other * other);
            out_v[node * 2 + comp] = s / fmaxf(nrm, 1e-12f);
        }
    }
}

extern "C" void kernel_launch(void* const* d_in, const int* in_sizes, int n_in,
                              void* d_out, int out_size, void* d_ws, size_t ws_size,
                              hipStream_t stream) {
    const float* h_in = (const float*)d_in[0];
    const float* x    = (const float*)d_in[1];
    const int*   eidx = (const int*)d_in[2];
    const float* embW = (const float*)d_in[3];
    const float* embb = (const float*)d_in[4];
    const float* eW1  = (const float*)d_in[5];
    const float* eb1  = (const float*)d_in[6];
    const float* eW2  = (const float*)d_in[7];
    const float* eb2  = (const float*)d_in[8];
    const float* nW1  = (const float*)d_in[9];
    const float* nb1  = (const float*)d_in[10];
    const float* nW2  = (const float*)d_in[11];
    const float* nb2  = (const float*)d_in[12];
    const float* vW1  = (const float*)d_in[13];
    const float* vb1  = (const float*)d_in[14];
    const float* vW2  = (const float*)d_in[15];
    const float* vb2  = (const float*)d_in[16];
    const float* cW1  = (const float*)d_in[17];
    const float* cb1  = (const float*)d_in[18];
    const float* cW2  = (const float*)d_in[19];
    const float* cb2  = (const float*)d_in[20];

    char* ws = (char*)d_ws;
    int* deg    = (int*)(ws + OFF_DEG);
    int* locEx  = (int*)(ws + OFF_LOCEX);
    int* bsum   = (int*)(ws + OFF_BSUM);
    int* boff   = (int*)(ws + OFF_BOFF);
    int* fill   = (int*)(ws + OFF_FILL);
    float* scat = (float*)(ws + OFF_SCAT);
    int* srow   = (int*)(ws + OFF_SROW);
    int* scol   = (int*)(ws + OFF_SCOL);
    float* m_i  = (float*)(ws + OFF_MI);
    float* hcur = (float*)(ws + OFF_H);
    f16* eW1s = (f16*)(ws + OFF_W);
    f16* eW2s = eW1s + 65536;
    f16* nW1s = eW2s + 32768;
    f16* nW2s = nW1s + 65536;
    f16* vW1s = nW2s + 32768;
    f16* cW1s = vW1s + 32768;

    // zero deg/locEx/bsum/boff/fill/scat/(srow/scol)/m_i in one shot
    hipMemsetAsync(ws, 0, OFF_MI + MI_BYTES, stream);

    prep_kernel<<<512, 256, 0, stream>>>(eW1, eW2, nW1, nW2, vW1, cW1,
                                         eW1s, eW2s, nW1s, nW2s, vW1s, cW1s);
    hist_kernel<<<(E_EDGES + 255) / 256, 256, 0, stream>>>(eidx, deg);
    scan1_kernel<<<NBLK, 256, 0, stream>>>(deg, locEx, bsum);
    scan2_kernel<<<1, 256, 0, stream>>>(bsum, boff);
    scatter_kernel<<<(E_EDGES + 255) / 256, 256, 0, stream>>>(eidx, locEx, boff,
                                                              fill, srow, scol);
    embed_kernel<<<(N_NODES * 128 + 255) / 256, 256, 0, stream>>>(h_in, embW, embb, hcur);

    // layer 1 (v overwritten next layer -> no coord/scatter)
    edge_kernel<<<E_EDGES / 64, 256, 0, stream>>>(srow, scol, x, hcur,
        eW1s, eW1, eb1, eW2s, eb2, cW1s, cb1, cW2, cb2, m_i, scat, 0);
    node_kernel<<<(N_NODES + 63) / 64, 256, 0, stream>>>(hcur, m_i,
        nW1s, nb1, nW2s, nb2);

    hipMemsetAsync(m_i, 0, MI_BYTES, stream);

    // layer 2 (with coord + scatter)
    edge_kernel<<<E_EDGES / 64, 256, 0, stream>>>(srow, scol, x, hcur,
        eW1s, eW1, eb1, eW2s, eb2, cW1s, cb1, cW2, cb2, m_i, scat, 1);
    node_kernel<<<(N_NODES + 63) / 64, 256, 0, stream>>>(hcur, m_i,
        nW1s, nb1, nW2s, nb2);

    final_kernel<<<(N_NODES + 63) / 64, 256, 0, stream>>>(hcur, x,
        vW1s, vb1, vW2, vb2, scat, deg, (float*)d_out);
}